// Round 1
// baseline (1573.258 us; speedup 1.0000x reference)
//
#include <hip/hip_runtime.h>
#include <cmath>

// DTASNN embedding: T=5 recurrent steps, each = conv(x, w_in) + conv(spike_prev, w_gate)
// (both 64ch -> 128ch, 3x3 SAME), split into current/gate halves, sigmoid-gated LIF
// update with per-channel decaying threshold, hard reset, avg spike readout.
//
// Shapes: events [8,5,64,64,64] f32 (binary), w_in/w_gate [128,64,3,3] f32,
// b_in/b_gate [128] f32, thresh_decay [64] f32. Output [8,64,64,64] f32.
//
// ws layout (floats): vmem [2M] | spikeA [2M] | spikeB [2M]  (25.2 MB total)

#define HW    64
#define CIN   64
#define COUT  64
#define TT    5
#define PLANE (HW * HW)          // 4096
#define LSTRIDE 72               // padded LDS row stride (72*4B = 288 = 16*18, b128-aligned rows)
#define LROWS   66               // 64 interior + top/bottom halo

// Accumulate 4 convolutions (same input plane, 4 weight sets) into 4 strip accumulators.
// Input rows read as aligned float4 from LDS; needed values are r[3 + j + kw].
__device__ __forceinline__ void conv_accum4(const float* __restrict__ lds,
    int h, int w0,
    const float* __restrict__ wa, const float* __restrict__ wb,
    const float* __restrict__ wc, const float* __restrict__ wd,
    float* __restrict__ A, float* __restrict__ B,
    float* __restrict__ C, float* __restrict__ D)
{
#pragma unroll
  for (int kh = 0; kh < 3; ++kh) {
    float r[24];
    const float4* rp = (const float4*)(lds + (h + kh) * LSTRIDE + w0);
#pragma unroll
    for (int q = 0; q < 6; ++q) {
      float4 v = rp[q];
      r[4*q+0] = v.x; r[4*q+1] = v.y; r[4*q+2] = v.z; r[4*q+3] = v.w;
    }
#pragma unroll
    for (int kw = 0; kw < 3; ++kw) {
      const float fa = wa[kh*3+kw], fb = wb[kh*3+kw];
      const float fc = wc[kh*3+kw], fd = wd[kh*3+kw];
#pragma unroll
      for (int j = 0; j < 16; ++j) {
        const float x = r[3 + j + kw];
        A[j] = fmaf(x, fa, A[j]);
        B[j] = fmaf(x, fb, B[j]);
        C[j] = fmaf(x, fc, C[j]);
        D[j] = fmaf(x, fd, D[j]);
      }
    }
  }
}

__global__ __launch_bounds__(256) void snn_step(
    const float* __restrict__ events,
    const float* __restrict__ w_in,
    const float* __restrict__ b_in,
    const float* __restrict__ w_gate,
    const float* __restrict__ b_gate,
    const float* __restrict__ tdecay,
    float* __restrict__ vmem,
    const float* __restrict__ s_src,
    float* __restrict__ s_dst,
    float* __restrict__ outp,
    int t)
{
  __shared__ float lx[LROWS * LSTRIDE];   // event plane (with zero halo = SAME padding)
  __shared__ float ls[LROWS * LSTRIDE];   // spike plane

  const int tid = threadIdx.x;
  const int blk = blockIdx.x;             // 256 blocks = b(8) x co-pair(32)
  const int b   = blk >> 5;
  const int co0 = (blk & 31) * 2;
  const int co1 = co0 + 1;

  // Zero everything once; interior is overwritten each ci, halo stays 0 (= SAME pad).
  for (int i = tid; i < LROWS * LSTRIDE; i += 256) { lx[i] = 0.f; ls[i] = 0.f; }

  const int h  = tid >> 2;                // 64 rows, 4 threads/row
  const int w0 = (tid & 3) * 16;          // 16-wide strip per thread

  float ac0[16], ag0[16], ac1[16], ag1[16];
#pragma unroll
  for (int j = 0; j < 16; ++j) { ac0[j]=0.f; ag0[j]=0.f; ac1[j]=0.f; ag1[j]=0.f; }

  // time-reversed events: step t reads events[b, TT-1-t]
  const float* evb = events + (size_t)(b * TT + (TT - 1 - t)) * CIN * PLANE + h * HW + w0;
  const float* ssb = s_src  + (size_t)b * CIN * PLANE + h * HW + w0;
  float* dlx = lx + (h + 1) * LSTRIDE + (w0 + 4);  // interior at [r+1][c+4], b128-aligned
  float* dls = ls + (h + 1) * LSTRIDE + (w0 + 4);

  for (int ci = 0; ci < CIN; ++ci) {
    const float4* gx = (const float4*)(evb + ci * PLANE);
    const float4* gs = (const float4*)(ssb + ci * PLANE);
    float4 x0 = gx[0], x1 = gx[1], x2 = gx[2], x3 = gx[3];
    float4 s0 = gs[0], s1 = gs[1], s2 = gs[2], s3 = gs[3];
    __syncthreads();                      // prior iter done reading LDS (also orders halo zeroing)
    ((float4*)dlx)[0] = x0; ((float4*)dlx)[1] = x1;
    ((float4*)dlx)[2] = x2; ((float4*)dlx)[3] = x3;
    ((float4*)dls)[0] = s0; ((float4*)dls)[1] = s1;
    ((float4*)dls)[2] = s2; ((float4*)dls)[3] = s3;
    __syncthreads();

    // weights are block-uniform -> scalar loads
    const float* wi_a = w_in   + (size_t)(co0 * CIN + ci) * 9;          // cur, co0
    const float* wi_b = w_in   + (size_t)((co0 + COUT) * CIN + ci) * 9; // gate, co0
    const float* wi_c = w_in   + (size_t)(co1 * CIN + ci) * 9;
    const float* wi_d = w_in   + (size_t)((co1 + COUT) * CIN + ci) * 9;
    conv_accum4(lx, h, w0, wi_a, wi_b, wi_c, wi_d, ac0, ag0, ac1, ag1);

    const float* wg_a = w_gate + (size_t)(co0 * CIN + ci) * 9;
    const float* wg_b = w_gate + (size_t)((co0 + COUT) * CIN + ci) * 9;
    const float* wg_c = w_gate + (size_t)(co1 * CIN + ci) * 9;
    const float* wg_d = w_gate + (size_t)((co1 + COUT) * CIN + ci) * 9;
    conv_accum4(ls, h, w0, wg_a, wg_b, wg_c, wg_d, ac0, ag0, ac1, ag1);
  }

  const float tf = (float)t;
  const bool t0 = (t == 0);
  const bool tL = (t == TT - 1);

  auto epilog = [&](const float* ac, const float* ag, int co) {
    const float bc = b_in[co]        + b_gate[co];
    const float bg = b_in[co + COUT] + b_gate[co + COUT];
    const float th = powf(tdecay[co], tf);        // THRESH=1.0
    const size_t base = (size_t)((b * COUT + co) * HW + h) * HW + w0;
    float* vp = vmem  + base;
    float* sp = s_dst + base;
    float* op = outp  + base;
#pragma unroll
    for (int j = 0; j < 16; ++j) {
      const float cur  = ac[j] + bc;
      const float gp   = ag[j] + bg;
      const float gate = 1.f / (1.f + expf(-gp));
      const float v    = gate * vp[j] + cur;      // vmem = gate*vmem + current
      const bool fired = (v >= th);               // == heaviside(v - th)
      vp[j] = fired ? 0.f : v;                    // hard reset to VRESET=0
      sp[j] = fired ? 1.f : 0.f;
      float o = (t0 ? 0.f : op[j]) + (fired ? 1.f : 0.f);
      if (tL) o *= 0.2f;                          // mean over T=5 (exact for int sums 0..5)
      op[j] = o;
    }
  };
  epilog(ac0, ag0, co0);
  epilog(ac1, ag1, co1);
}

extern "C" void kernel_launch(void* const* d_in, const int* in_sizes, int n_in,
                              void* d_out, int out_size, void* d_ws, size_t ws_size,
                              hipStream_t stream) {
  const float* events = (const float*)d_in[0];
  const float* w_in   = (const float*)d_in[1];
  const float* b_in   = (const float*)d_in[2];
  const float* w_gate = (const float*)d_in[3];
  const float* b_gate = (const float*)d_in[4];
  const float* tdec   = (const float*)d_in[5];
  float* out = (float*)d_out;

  float* ws   = (float*)d_ws;
  const size_t NP = (size_t)8 * COUT * PLANE;   // 2,097,152
  float* vmem = ws;
  float* sA   = ws + NP;
  float* sB   = ws + 2 * NP;

  // zero vmem + spikeA (spikeB fully written at t=0 before first read)
  hipMemsetAsync(d_ws, 0, 2 * NP * sizeof(float), stream);

  dim3 grid(256), block(256);
  for (int t = 0; t < TT; ++t) {
    const float* ssrc = (t & 1) ? sB : sA;
    float*       sdst = (t & 1) ? sA : sB;
    hipLaunchKernelGGL(snn_step, grid, block, 0, stream,
                       events, w_in, b_in, w_gate, b_gate, tdec,
                       vmem, ssrc, sdst, out, t);
  }
}

// Round 2
// 1010.002 us; speedup vs baseline: 1.5577x; 1.5577x over previous
//
#include <hip/hip_runtime.h>
#include <cmath>

// DTASNN embedding: T=5 recurrent steps, each = conv(x, w_in) + conv(spike_prev, w_gate)
// (both 64ch -> 128ch, 3x3 SAME), sigmoid-gated LIF update, hard reset, avg readout.
//
// R2 changes vs R1 (which was LDS-conflict + occupancy bound):
//  - LSTRIDE 72 -> 68: 68 mod 32 = 4, so wave64 ds_read_b128 base banks tile all 32
//    banks 2-way (free) instead of 16-way on banks {0,8,16,24}.
//  - 512 threads/block (8 waves = 2/SIMD, occupancy 12->25%), 8-wide strips.
//  - global prefetch of ci+1 issued before compute(ci).
//
// ws layout (floats): vmem [2M] | spikeA [2M] | spikeB [2M]

#define HW    64
#define CIN   64
#define COUT  64
#define TT    5
#define PLANE (HW * HW)            // 4096
#define LSTRIDE 68                 // 68 mod 32 == 4 -> conflict-free b128 pattern
#define LROWS   66                 // top halo + 64 interior + bottom halo
#define LPLANE  (LROWS * LSTRIDE + 4)  // +4: last b128 read overhangs row 65

// Accumulate 4 convolutions (same input plane, 4 weight sets) into 4 8-wide strips.
__device__ __forceinline__ void conv_accum4(const float* __restrict__ lds,
    int h, int w0,
    const float* __restrict__ wa, const float* __restrict__ wb,
    const float* __restrict__ wc, const float* __restrict__ wd,
    float* __restrict__ A, float* __restrict__ B,
    float* __restrict__ C, float* __restrict__ D)
{
#pragma unroll
  for (int kh = 0; kh < 3; ++kh) {
    float r[16];
    const float4* rp = (const float4*)(lds + (h + kh) * LSTRIDE + w0);
#pragma unroll
    for (int q = 0; q < 4; ++q) {
      float4 v = rp[q];
      r[4*q+0] = v.x; r[4*q+1] = v.y; r[4*q+2] = v.z; r[4*q+3] = v.w;
    }
#pragma unroll
    for (int kw = 0; kw < 3; ++kw) {
      const float fa = wa[kh*3+kw], fb = wb[kh*3+kw];
      const float fc = wc[kh*3+kw], fd = wd[kh*3+kw];
#pragma unroll
      for (int j = 0; j < 8; ++j) {
        const float x = r[3 + j + kw];   // col w0+j-1+kw (dword col+4, halo at 3/68)
        A[j] = fmaf(x, fa, A[j]);
        B[j] = fmaf(x, fb, B[j]);
        C[j] = fmaf(x, fc, C[j]);
        D[j] = fmaf(x, fd, D[j]);
      }
    }
  }
}

__global__ __launch_bounds__(512) void snn_step(
    const float* __restrict__ events,
    const float* __restrict__ w_in,
    const float* __restrict__ b_in,
    const float* __restrict__ w_gate,
    const float* __restrict__ b_gate,
    const float* __restrict__ tdecay,
    float* __restrict__ vmem,
    const float* __restrict__ s_src,
    float* __restrict__ s_dst,
    float* __restrict__ outp,
    int t)
{
  __shared__ float lx[LPLANE];   // event plane (zero halo = SAME padding)
  __shared__ float ls[LPLANE];   // spike plane

  const int tid = threadIdx.x;
  const int blk = blockIdx.x;              // 256 blocks = b(8) x co-pair(32)
  const int b   = blk >> 5;
  const int co0 = (blk & 31) * 2;
  const int co1 = co0 + 1;

  // Zero once; interior overwritten each ci, halo (rows 0/65, dwords 0..3 of
  // each row = right-halo-of-previous + left halo) stays 0 = SAME padding.
  for (int i = tid; i < LPLANE; i += 512) { lx[i] = 0.f; ls[i] = 0.f; }

  const int h  = tid >> 3;                 // 64 rows, 8 threads/row
  const int w0 = (tid & 7) * 8;            // 8-wide strip per thread

  float ac0[8], ag0[8], ac1[8], ag1[8];
#pragma unroll
  for (int j = 0; j < 8; ++j) { ac0[j]=0.f; ag0[j]=0.f; ac1[j]=0.f; ag1[j]=0.f; }

  // time-reversed events: step t reads events[b, TT-1-t]
  const float* evb = events + (size_t)(b * TT + (TT - 1 - t)) * CIN * PLANE + h * HW + w0;
  const float* ssb = s_src  + (size_t)b * CIN * PLANE + h * HW + w0;
  float* dlx = lx + (h + 1) * LSTRIDE + (w0 + 4);  // interior cols at dword 4..67
  float* dls = ls + (h + 1) * LSTRIDE + (w0 + 4);

  // prefetch ci=0
  float4 x0 = ((const float4*)evb)[0], x1 = ((const float4*)evb)[1];
  float4 s0 = ((const float4*)ssb)[0], s1 = ((const float4*)ssb)[1];

  for (int ci = 0; ci < CIN; ++ci) {
    __syncthreads();                       // prior iter done reading LDS
    ((float4*)dlx)[0] = x0; ((float4*)dlx)[1] = x1;
    ((float4*)dls)[0] = s0; ((float4*)dls)[1] = s1;
    __syncthreads();

    if (ci + 1 < CIN) {                    // issue next-ci loads ahead of compute
      const float* nx = evb + (ci + 1) * PLANE;
      const float* ns = ssb + (ci + 1) * PLANE;
      x0 = ((const float4*)nx)[0]; x1 = ((const float4*)nx)[1];
      s0 = ((const float4*)ns)[0]; s1 = ((const float4*)ns)[1];
    }

    // weights are block-uniform -> scalar loads, SGPR-operand FMAs
    const float* wi_a = w_in   + (size_t)(co0 * CIN + ci) * 9;          // cur, co0
    const float* wi_b = w_in   + (size_t)((co0 + COUT) * CIN + ci) * 9; // gate, co0
    const float* wi_c = w_in   + (size_t)(co1 * CIN + ci) * 9;
    const float* wi_d = w_in   + (size_t)((co1 + COUT) * CIN + ci) * 9;
    conv_accum4(lx, h, w0, wi_a, wi_b, wi_c, wi_d, ac0, ag0, ac1, ag1);

    const float* wg_a = w_gate + (size_t)(co0 * CIN + ci) * 9;
    const float* wg_b = w_gate + (size_t)((co0 + COUT) * CIN + ci) * 9;
    const float* wg_c = w_gate + (size_t)(co1 * CIN + ci) * 9;
    const float* wg_d = w_gate + (size_t)((co1 + COUT) * CIN + ci) * 9;
    conv_accum4(ls, h, w0, wg_a, wg_b, wg_c, wg_d, ac0, ag0, ac1, ag1);
  }

  const float tf = (float)t;
  const bool t0 = (t == 0);
  const bool tL = (t == TT - 1);

  auto epilog = [&](const float* ac, const float* ag, int co) {
    const float bc = b_in[co]        + b_gate[co];
    const float bg = b_in[co + COUT] + b_gate[co + COUT];
    const float th = powf(tdecay[co], tf);        // THRESH=1.0
    const size_t base = (size_t)((b * COUT + co) * HW + h) * HW + w0;
    float* vp = vmem  + base;
    float* sp = s_dst + base;
    float* op = outp  + base;
#pragma unroll
    for (int j = 0; j < 8; ++j) {
      const float cur  = ac[j] + bc;
      const float gp   = ag[j] + bg;
      const float gate = 1.f / (1.f + expf(-gp));
      const float v    = gate * vp[j] + cur;      // vmem = gate*vmem + current
      const bool fired = (v >= th);               // heaviside(v - th)
      vp[j] = fired ? 0.f : v;                    // hard reset to VRESET=0
      sp[j] = fired ? 1.f : 0.f;
      float o = (t0 ? 0.f : op[j]) + (fired ? 1.f : 0.f);
      if (tL) o *= 0.2f;                          // mean over T=5
      op[j] = o;
    }
  };
  epilog(ac0, ag0, co0);
  epilog(ac1, ag1, co1);
}

extern "C" void kernel_launch(void* const* d_in, const int* in_sizes, int n_in,
                              void* d_out, int out_size, void* d_ws, size_t ws_size,
                              hipStream_t stream) {
  const float* events = (const float*)d_in[0];
  const float* w_in   = (const float*)d_in[1];
  const float* b_in   = (const float*)d_in[2];
  const float* w_gate = (const float*)d_in[3];
  const float* b_gate = (const float*)d_in[4];
  const float* tdec   = (const float*)d_in[5];
  float* out = (float*)d_out;

  float* ws   = (float*)d_ws;
  const size_t NP = (size_t)8 * COUT * PLANE;   // 2,097,152
  float* vmem = ws;
  float* sA   = ws + NP;
  float* sB   = ws + 2 * NP;

  // zero vmem + spikeA (spikeB fully written at t=0 before first read)
  hipMemsetAsync(d_ws, 0, 2 * NP * sizeof(float), stream);

  dim3 grid(256), block(512);
  for (int t = 0; t < TT; ++t) {
    const float* ssrc = (t & 1) ? sB : sA;
    float*       sdst = (t & 1) ? sA : sB;
    hipLaunchKernelGGL(snn_step, grid, block, 0, stream,
                       events, w_in, b_in, w_gate, b_gate, tdec,
                       vmem, ssrc, sdst, out, t);
  }
}